// Round 7
// baseline (647.903 us; speedup 1.0000x reference)
//
#include <hip/hip_runtime.h>
#include <hip/hip_bf16.h>

// LightGCN forward: bucketed CSR build (write-locality-aware) + 3-hop pull SpMM
// (wave-per-row, 8-wide MLP unroll, hop 3 sliced to loss rows) + InfoNCE loss.

#define NUM_USERS 100000
#define NUM_ITEMS 50000
#define NTOT      150000
#define DIM       64
#define NNZ_C     4000000
#define BATCH     4096
#define NUM_NEG   8
#define NSLICE    (BATCH + BATCH + NUM_NEG * BATCH)   // 40960 hop-3 rows

#define RPB        128                                 // rows per bucket
#define NBUCKET    ((NTOT + RPB - 1) / RPB)            // 1172
#define BIN_BLOCKS 1024                                // 4 blocks/CU: latency hiding >> run length
#define EDGES_PER_BIN ((NNZ_C + BIN_BLOCKS - 1) / BIN_BLOCKS)  // 3907
#define STAGE_CAP  6144    // records staged per bucket in csr_fix (mean 3413)

using bf16 = __hip_bfloat16;

// ---- zero an int buffer ---------------------------------------------------
__global__ void zero_ints(int* __restrict__ a, int n) {
    int i = blockIdx.x * blockDim.x + threadIdx.x;
    if (i < n) a[i] = 0;
}

// ---- x0 = bf16(concat(user_emb, item_emb)); zero loss_accum ---------------
__global__ void convert_concat(const float* __restrict__ ue, const float* __restrict__ ie,
                               bf16* __restrict__ x0, float* __restrict__ loss_accum) {
    int i = blockIdx.x * blockDim.x + threadIdx.x;   // pair index
    if (i == 0) loss_accum[0] = 0.0f;
    if (i >= NTOT * DIM / 2) return;
    int base = i * 2;
    float2 v = (base < NUM_USERS * DIM)
                   ? ((const float2*)ue)[i]
                   : ((const float2*)ie)[i - NUM_USERS * DIM / 2];
    x0[base]     = __float2bfloat16(v.x);
    x0[base + 1] = __float2bfloat16(v.y);
}

// ---- bucket histogram: LDS sub-hist per block, one global merge -----------
__global__ void bucket_hist_k(const int* __restrict__ rows, int* __restrict__ bhist) {
    __shared__ int lh[NBUCKET];
    for (int i = threadIdx.x; i < NBUCKET; i += blockDim.x) lh[i] = 0;
    __syncthreads();
    int stride = gridDim.x * blockDim.x;
    #pragma unroll 4
    for (int e = blockIdx.x * blockDim.x + threadIdx.x; e < NNZ_C; e += stride)
        atomicAdd(&lh[rows[e] >> 7], 1);
    __syncthreads();
    for (int i = threadIdx.x; i < NBUCKET; i += blockDim.x)
        if (lh[i]) atomicAdd(&bhist[i], lh[i]);
}

// ---- exclusive scan over 1172 bucket counts (single block) ----------------
__global__ void bucket_scan_k(const int* __restrict__ bhist, int* __restrict__ bbase,
                              int* __restrict__ bcur) {
    __shared__ int sm[256];
    const int K = (NBUCKET + 255) / 256;   // 5
    int t = threadIdx.x;
    int loc[8];
    int s = 0;
    for (int k = 0; k < K; ++k) {
        int i = t * K + k;
        loc[k] = (i < NBUCKET) ? bhist[i] : 0;
        s += loc[k];
    }
    sm[t] = s;
    __syncthreads();
    for (int o = 1; o < 256; o <<= 1) {
        int v = (t >= o) ? sm[t - o] : 0;
        __syncthreads();
        sm[t] += v;
        __syncthreads();
    }
    int run = sm[t] - s;   // exclusive prefix for this thread
    for (int k = 0; k < K; ++k) {
        int i = t * K + k;
        if (i < NBUCKET) { bbase[i] = run; bcur[i] = run; }
        run += loc[k];
    }
    if (t == 255) bbase[NBUCKET] = NNZ_C;
}

// ---- bin pass: append packed records into contiguous bucket spans ---------
// Per block: LDS chunk hist -> one global span reservation per bucket ->
// append (row_lo<<18 | col, val). Spans contiguous per (block,bucket).
__global__ void bin_k(const int* __restrict__ rows, const int* __restrict__ cols,
                      const float* __restrict__ vals, int* __restrict__ bcur,
                      int2* __restrict__ brec) {
    __shared__ int lh[NBUCKET];
    __shared__ int lb[NBUCKET];
    int t = threadIdx.x;
    for (int i = t; i < NBUCKET; i += 256) lh[i] = 0;
    __syncthreads();
    int e0 = blockIdx.x * EDGES_PER_BIN;
    int e1 = e0 + EDGES_PER_BIN; if (e1 > NNZ_C) e1 = NNZ_C;
    #pragma unroll 4
    for (int e = e0 + t; e < e1; e += 256) atomicAdd(&lh[rows[e] >> 7], 1);
    __syncthreads();
    for (int i = t; i < NBUCKET; i += 256) {
        int c = lh[i];
        lb[i] = c ? atomicAdd(&bcur[i], c) : 0;
        lh[i] = 0;                         // reuse as local write cursor
    }
    __syncthreads();
    #pragma unroll 4
    for (int e = e0 + t; e < e1; e += 256) {
        int r = rows[e];
        int b = r >> 7;
        int p = lb[b] + atomicAdd(&lh[b], 1);
        brec[p] = make_int2(((r & 127) << 18) | cols[e], __float_as_int(vals[e]));
    }
}

// ---- per-bucket in-place reorder into row-sorted CSR + rp -----------------
__global__ void csr_fix_k(int2* __restrict__ brec, const int* __restrict__ bbase,
                          int* __restrict__ rp) {
    __shared__ int2 stage[STAGE_CAP];
    __shared__ int lh[RPB], lb[RPB], lc[RPB], sm[RPB];
    int b = blockIdx.x;
    int t = threadIdx.x;
    int s = bbase[b], e = bbase[b + 1];
    int cnt = e - s;
    if (t < RPB) lh[t] = 0;
    __syncthreads();
    for (int j = t; j < cnt; j += 256) {
        int2 rc = brec[s + j];
        stage[j] = rc;
        atomicAdd(&lh[(rc.x >> 18) & 127], 1);
    }
    __syncthreads();
    if (t < RPB) sm[t] = lh[t];
    __syncthreads();
    for (int o = 1; o < RPB; o <<= 1) {
        int v = 0;
        if (t < RPB && t >= o) v = sm[t - o];
        __syncthreads();
        if (t < RPB) sm[t] += v;
        __syncthreads();
    }
    if (t < RPB) {
        int ex = sm[t] - lh[t];
        lb[t] = ex;
        lc[t] = 0;
        int row = b * RPB + t;
        if (row < NTOT) rp[row] = s + ex;
        if (row == NTOT - 1) rp[NTOT] = NNZ_C;
    }
    __syncthreads();
    for (int j = t; j < cnt; j += 256) {
        int2 rc = stage[j];
        int rl = (rc.x >> 18) & 127;
        int p = s + lb[rl] + atomicAdd(&lc[rl], 1);
        brec[p] = make_int2(rc.x & 0x3FFFF, rc.y);   // final CSR record (col, val)
    }
}

// ---- pull-mode SpMM body: 8-wide edge unroll, 4 accumulators --------------
__device__ __forceinline__ float spmm_row(const bf16* __restrict__ x,
                                          const int2* __restrict__ cpack,
                                          int s, int e, int lane) {
    float a0 = 0.f, a1 = 0.f, a2 = 0.f, a3 = 0.f;
    int j = s;
    for (; j + 8 <= e; j += 8) {
        int2 p0 = cpack[j + 0], p1 = cpack[j + 1], p2 = cpack[j + 2], p3 = cpack[j + 3];
        int2 p4 = cpack[j + 4], p5 = cpack[j + 5], p6 = cpack[j + 6], p7 = cpack[j + 7];
        float g0 = __bfloat162float(x[p0.x * DIM + lane]);
        float g1 = __bfloat162float(x[p1.x * DIM + lane]);
        float g2 = __bfloat162float(x[p2.x * DIM + lane]);
        float g3 = __bfloat162float(x[p3.x * DIM + lane]);
        float g4 = __bfloat162float(x[p4.x * DIM + lane]);
        float g5 = __bfloat162float(x[p5.x * DIM + lane]);
        float g6 = __bfloat162float(x[p6.x * DIM + lane]);
        float g7 = __bfloat162float(x[p7.x * DIM + lane]);
        a0 = fmaf(__int_as_float(p0.y), g0, a0);
        a1 = fmaf(__int_as_float(p1.y), g1, a1);
        a2 = fmaf(__int_as_float(p2.y), g2, a2);
        a3 = fmaf(__int_as_float(p3.y), g3, a3);
        a0 = fmaf(__int_as_float(p4.y), g4, a0);
        a1 = fmaf(__int_as_float(p5.y), g5, a1);
        a2 = fmaf(__int_as_float(p6.y), g6, a2);
        a3 = fmaf(__int_as_float(p7.y), g7, a3);
    }
    for (; j < e; ++j) {
        int2 p = cpack[j];
        a0 = fmaf(__int_as_float(p.y), __bfloat162float(x[p.x * DIM + lane]), a0);
    }
    return (a0 + a1) + (a2 + a3);
}

// ---- full SpMM: one wave per row ------------------------------------------
__global__ void spmm_k(const bf16* __restrict__ x, const int* __restrict__ rp,
                       const int2* __restrict__ cpack, bf16* __restrict__ y) {
    int row  = (blockIdx.x * blockDim.x + threadIdx.x) >> 6;
    int lane = threadIdx.x & 63;
    if (row >= NTOT) return;
    float a = spmm_row(x, cpack, rp[row], rp[row + 1], lane);
    y[row * DIM + lane] = __float2bfloat16(a);
}

// ---- sliced SpMM for hop 3: only rows the loss reads ----------------------
__global__ void spmm_sliced_k(const bf16* __restrict__ x, const int* __restrict__ rp,
                              const int2* __restrict__ cpack,
                              const int* __restrict__ users, const int* __restrict__ items,
                              const int* __restrict__ negs, bf16* __restrict__ y) {
    int w    = (blockIdx.x * blockDim.x + threadIdx.x) >> 6;
    int lane = threadIdx.x & 63;
    if (w >= NSLICE) return;
    int row = (w < BATCH)     ? users[w]
            : (w < 2 * BATCH) ? NUM_USERS + items[w - BATCH]
                              : NUM_USERS + negs[w - 2 * BATCH];
    float a = spmm_row(x, cpack, rp[row], rp[row + 1], lane);
    y[row * DIM + lane] = __float2bfloat16(a);   // duplicate rows rewrite same value: benign
}

// ---- InfoNCE loss from the four hop buffers (acc/4 on the fly) ------------
__global__ void loss_k(const bf16* __restrict__ x0, const bf16* __restrict__ x1,
                       const bf16* __restrict__ x2, const bf16* __restrict__ x3,
                       const int* __restrict__ users, const int* __restrict__ items,
                       const int* __restrict__ negs, float* __restrict__ loss_accum) {
    int w    = (blockIdx.x * blockDim.x + threadIdx.x) >> 6;
    int lane = threadIdx.x & 63;
    if (w >= BATCH) return;
    auto rowv = [&](int r) -> float {
        int o = r * DIM + lane;
        return (__bfloat162float(x0[o]) + __bfloat162float(x1[o]) +
                __bfloat162float(x2[o]) + __bfloat162float(x3[o])) * 0.25f;
    };
    float ue = rowv(users[w]);
    float ie = rowv(NUM_USERS + items[w]);
    float p = ue * ie;
    for (int o = 32; o > 0; o >>= 1) p += __shfl_xor(p, o, 64);
    float pe = expf(p);
    float ne = 0.0f;
    for (int k = 0; k < NUM_NEG; ++k) {
        float q = ue * rowv(NUM_USERS + negs[k * BATCH + w]);
        for (int o = 32; o > 0; o >>= 1) q += __shfl_xor(q, o, 64);
        ne += expf(q);
    }
    if (lane == 0) atomicAdd(loss_accum, logf((pe + ne) / pe));
}

__global__ void finalize_k(const float* __restrict__ loss_accum, float* __restrict__ out) {
    out[0] = loss_accum[0] * (1.0f / BATCH);
}

__global__ void sentinel_k(float* __restrict__ out) {
    out[0] = -1.0f;
}

extern "C" void kernel_launch(void* const* d_in, const int* in_sizes, int n_in,
                              void* d_out, int out_size, void* d_ws, size_t ws_size,
                              hipStream_t stream) {
    const float* user_emb = (const float*)d_in[0];
    const float* item_emb = (const float*)d_in[1];
    const float* A_vals   = (const float*)d_in[2];
    const int*   A_rows   = (const int*)d_in[3];
    const int*   A_cols   = (const int*)d_in[4];
    const int*   users    = (const int*)d_in[5];
    const int*   items    = (const int*)d_in[6];
    const int*   negs     = (const int*)d_in[7];
    float* out = (float*)d_out;

    char* ws = (char*)d_ws;
    size_t off = 0;
    auto carve = [&](size_t bytes) -> char* {
        char* p = ws + off;
        off = (off + bytes + 255) & ~(size_t)255;
        return p;
    };
    bf16*  x0        = (bf16*)carve((size_t)NTOT * DIM * 2);   // 19.2 MB
    bf16*  x1        = (bf16*)carve((size_t)NTOT * DIM * 2);
    bf16*  x2        = (bf16*)carve((size_t)NTOT * DIM * 2);
    bf16*  x3        = (bf16*)carve((size_t)NTOT * DIM * 2);
    int2*  brec      = (int2*)carve((size_t)NNZ_C * 8);        // 32 MB (binned, then CSR in place)
    int*   rp        = (int*)carve((size_t)(NTOT + 1) * 4);
    int*   bhist     = (int*)carve((size_t)NBUCKET * 4);
    int*   bbase     = (int*)carve((size_t)(NBUCKET + 1) * 4);
    int*   bcur      = (int*)carve((size_t)NBUCKET * 4);
    float* loss_accum= (float*)carve(256);

    if (off > ws_size) {
        sentinel_k<<<1, 1, 0, stream>>>(out);
        return;
    }

    convert_concat<<<(NTOT * DIM / 2 + 255) / 256, 256, 0, stream>>>(user_emb, item_emb, x0, loss_accum);

    // bucketed CSR build
    zero_ints<<<(NBUCKET + 255) / 256, 256, 0, stream>>>(bhist, NBUCKET);
    bucket_hist_k<<<1024, 256, 0, stream>>>(A_rows, bhist);
    bucket_scan_k<<<1, 256, 0, stream>>>(bhist, bbase, bcur);
    bin_k<<<BIN_BLOCKS, 256, 0, stream>>>(A_rows, A_cols, A_vals, bcur, brec);
    csr_fix_k<<<NBUCKET, 256, 0, stream>>>(brec, bbase, rp);

    // hops 1-2 full, hop 3 sliced to loss rows
    const int spmm_blocks = (NTOT * 64 + 255) / 256;
    spmm_k<<<spmm_blocks, 256, 0, stream>>>(x0, rp, brec, x1);
    spmm_k<<<spmm_blocks, 256, 0, stream>>>(x1, rp, brec, x2);
    spmm_sliced_k<<<(NSLICE * 64 + 255) / 256, 256, 0, stream>>>(x2, rp, brec, users, items, negs, x3);

    // loss
    loss_k<<<(BATCH * 64 + 255) / 256, 256, 0, stream>>>(x0, x1, x2, x3, users, items, negs, loss_accum);
    finalize_k<<<1, 1, 0, stream>>>(loss_accum, out);
}

// Round 8
// 647.539 us; speedup vs baseline: 1.0006x; 1.0006x over previous
//
#include <hip/hip_runtime.h>
#include <hip/hip_bf16.h>

// LightGCN forward: bucketed CSR build with LDS-multisplit bin pass (coalesced
// flush) + 3-hop pull SpMM (wave-per-row, 16-wide MLP unroll, hop 3 sliced to
// loss rows) + InfoNCE loss.

#define NUM_USERS 100000
#define NUM_ITEMS 50000
#define NTOT      150000
#define DIM       64
#define NNZ_C     4000000
#define BATCH     4096
#define NUM_NEG   8
#define NSLICE    (BATCH + BATCH + NUM_NEG * BATCH)   // 40960 hop-3 rows

#define RPB        192                                 // rows per bucket
#define NBUCKET    ((NTOT + RPB - 1) / RPB)            // 782
#define BIN_BLOCKS 1024
#define EDGES_PER_BIN ((NNZ_C + BIN_BLOCKS - 1) / BIN_BLOCKS)  // 3907
#define STAGE_CAP  6656    // csr_fix staging; mean 5115, sd 71 -> +21 sigma

using bf16 = __hip_bfloat16;

// ---- zero an int buffer ---------------------------------------------------
__global__ void zero_ints(int* __restrict__ a, int n) {
    int i = blockIdx.x * blockDim.x + threadIdx.x;
    if (i < n) a[i] = 0;
}

// ---- x0 = bf16(concat(user_emb, item_emb)); zero loss_accum ---------------
__global__ void convert_concat(const float* __restrict__ ue, const float* __restrict__ ie,
                               bf16* __restrict__ x0, float* __restrict__ loss_accum) {
    int i = blockIdx.x * blockDim.x + threadIdx.x;   // pair index
    if (i == 0) loss_accum[0] = 0.0f;
    if (i >= NTOT * DIM / 2) return;
    int base = i * 2;
    float2 v = (base < NUM_USERS * DIM)
                   ? ((const float2*)ue)[i]
                   : ((const float2*)ie)[i - NUM_USERS * DIM / 2];
    x0[base]     = __float2bfloat16(v.x);
    x0[base + 1] = __float2bfloat16(v.y);
}

// ---- bucket histogram: LDS sub-hist per block, one global merge -----------
__global__ void bucket_hist_k(const int* __restrict__ rows, int* __restrict__ bhist) {
    __shared__ int lh[NBUCKET];
    for (int i = threadIdx.x; i < NBUCKET; i += blockDim.x) lh[i] = 0;
    __syncthreads();
    int stride = gridDim.x * blockDim.x;
    #pragma unroll 4
    for (int e = blockIdx.x * blockDim.x + threadIdx.x; e < NNZ_C; e += stride)
        atomicAdd(&lh[rows[e] / RPB], 1);
    __syncthreads();
    for (int i = threadIdx.x; i < NBUCKET; i += blockDim.x)
        if (lh[i]) atomicAdd(&bhist[i], lh[i]);
}

// ---- exclusive scan over NBUCKET bucket counts (single block) -------------
__global__ void bucket_scan_k(const int* __restrict__ bhist, int* __restrict__ bbase,
                              int* __restrict__ bcur) {
    __shared__ int sm[256];
    const int K = (NBUCKET + 255) / 256;   // 4
    int t = threadIdx.x;
    int loc[8];
    int s = 0;
    for (int k = 0; k < K; ++k) {
        int i = t * K + k;
        loc[k] = (i < NBUCKET) ? bhist[i] : 0;
        s += loc[k];
    }
    sm[t] = s;
    __syncthreads();
    for (int o = 1; o < 256; o <<= 1) {
        int v = (t >= o) ? sm[t - o] : 0;
        __syncthreads();
        sm[t] += v;
        __syncthreads();
    }
    int run = sm[t] - s;   // exclusive prefix for this thread
    for (int k = 0; k < K; ++k) {
        int i = t * K + k;
        if (i < NBUCKET) { bbase[i] = run; bcur[i] = run; }
        run += loc[k];
    }
    if (t == 255) bbase[NBUCKET] = NNZ_C;
}

// ---- bin pass v2: LDS multisplit, then run-coalesced flush ----------------
// Records are placed bucket-sorted into LDS (stage) with their final global
// slot (pdst); the flush reads lane-consecutive LDS and stores to global in
// ~5-record contiguous runs instead of 64 scattered lines per wave.
__global__ void __launch_bounds__(256) bin_k(const int* __restrict__ rows,
                                             const int* __restrict__ cols,
                                             const float* __restrict__ vals,
                                             int* __restrict__ bcur,
                                             int2* __restrict__ brec) {
    __shared__ int2 stage[EDGES_PER_BIN];   // 31.3 KB
    __shared__ int  pdst[EDGES_PER_BIN];    // 15.6 KB
    __shared__ int  lh[NBUCKET], lofs[NBUCKET], gbase[NBUCKET];  // 9.4 KB
    __shared__ int  sm[256];
    int t = threadIdx.x;
    for (int i = t; i < NBUCKET; i += 256) lh[i] = 0;
    __syncthreads();
    int e0 = blockIdx.x * EDGES_PER_BIN;
    int e1 = e0 + EDGES_PER_BIN; if (e1 > NNZ_C) e1 = NNZ_C;
    #pragma unroll 4
    for (int e = e0 + t; e < e1; e += 256) atomicAdd(&lh[rows[e] / RPB], 1);
    __syncthreads();
    // local exclusive scan lh -> lofs
    {
        const int K = (NBUCKET + 255) / 256;   // 4
        int loc[4];
        int s = 0;
        for (int k = 0; k < K; ++k) {
            int i = t * K + k;
            loc[k] = (i < NBUCKET) ? lh[i] : 0;
            s += loc[k];
        }
        sm[t] = s;
        __syncthreads();
        for (int o = 1; o < 256; o <<= 1) {
            int v = (t >= o) ? sm[t - o] : 0;
            __syncthreads();
            sm[t] += v;
            __syncthreads();
        }
        int run = sm[t] - s;
        for (int k = 0; k < K; ++k) {
            int i = t * K + k;
            if (i < NBUCKET) lofs[i] = run;
            run += loc[k];
        }
    }
    __syncthreads();
    // reserve global spans; reset lh as placement cursor
    for (int i = t; i < NBUCKET; i += 256) {
        int c = lh[i];
        gbase[i] = c ? atomicAdd(&bcur[i], c) : 0;
        lh[i] = 0;
    }
    __syncthreads();
    // placement (bucket-sorted into LDS)
    #pragma unroll 2
    for (int e = e0 + t; e < e1; e += 256) {
        int r = rows[e];
        int b = r / RPB;
        int rank = atomicAdd(&lh[b], 1);
        int j = lofs[b] + rank;
        stage[j] = make_int2(((r - b * RPB) << 18) | cols[e], __float_as_int(vals[e]));
        pdst[j]  = gbase[b] + rank;
    }
    __syncthreads();
    // run-coalesced flush
    int cnt = e1 - e0;
    for (int j = t; j < cnt; j += 256)
        brec[pdst[j]] = stage[j];
}

// ---- per-bucket in-place reorder into row-sorted CSR + rp -----------------
__global__ void csr_fix_k(int2* __restrict__ brec, const int* __restrict__ bbase,
                          int* __restrict__ rp) {
    __shared__ int2 stage[STAGE_CAP];
    __shared__ int lh[RPB], lb[RPB], lc[RPB], sm[RPB];
    int b = blockIdx.x;
    int t = threadIdx.x;
    int s = bbase[b], e = bbase[b + 1];
    int cnt = e - s;
    if (t < RPB) lh[t] = 0;
    __syncthreads();
    for (int j = t; j < cnt; j += 256) {
        int2 rc = brec[s + j];
        stage[j] = rc;
        atomicAdd(&lh[(rc.x >> 18) & 255], 1);
    }
    __syncthreads();
    if (t < RPB) sm[t] = lh[t];
    __syncthreads();
    for (int o = 1; o < RPB; o <<= 1) {
        int v = 0;
        if (t < RPB && t >= o) v = sm[t - o];
        __syncthreads();
        if (t < RPB) sm[t] += v;
        __syncthreads();
    }
    if (t < RPB) {
        int ex = sm[t] - lh[t];
        lb[t] = ex;
        lc[t] = 0;
        int row = b * RPB + t;
        if (row < NTOT) rp[row] = s + ex;
        if (row == NTOT - 1) rp[NTOT] = NNZ_C;
    }
    __syncthreads();
    for (int j = t; j < cnt; j += 256) {
        int2 rc = stage[j];
        int rl = (rc.x >> 18) & 255;
        int p = s + lb[rl] + atomicAdd(&lc[rl], 1);
        brec[p] = make_int2(rc.x & 0x3FFFF, rc.y);   // final CSR record (col, val)
    }
}

// ---- pull-mode SpMM body: 16-wide edge unroll, 8 accumulators -------------
__device__ __forceinline__ float spmm_row(const bf16* __restrict__ x,
                                          const int2* __restrict__ cpack,
                                          int s, int e, int lane) {
    float acc[8];
    #pragma unroll
    for (int k = 0; k < 8; ++k) acc[k] = 0.0f;
    int j = s;
    for (; j + 16 <= e; j += 16) {
        int2 p[16];
        #pragma unroll
        for (int k = 0; k < 16; ++k) p[k] = cpack[j + k];
        float g[16];
        #pragma unroll
        for (int k = 0; k < 16; ++k) g[k] = __bfloat162float(x[p[k].x * DIM + lane]);
        #pragma unroll
        for (int k = 0; k < 16; ++k) acc[k & 7] = fmaf(__int_as_float(p[k].y), g[k], acc[k & 7]);
    }
    for (; j + 4 <= e; j += 4) {
        int2 p0 = cpack[j], p1 = cpack[j + 1], p2 = cpack[j + 2], p3 = cpack[j + 3];
        float g0 = __bfloat162float(x[p0.x * DIM + lane]);
        float g1 = __bfloat162float(x[p1.x * DIM + lane]);
        float g2 = __bfloat162float(x[p2.x * DIM + lane]);
        float g3 = __bfloat162float(x[p3.x * DIM + lane]);
        acc[0] = fmaf(__int_as_float(p0.y), g0, acc[0]);
        acc[1] = fmaf(__int_as_float(p1.y), g1, acc[1]);
        acc[2] = fmaf(__int_as_float(p2.y), g2, acc[2]);
        acc[3] = fmaf(__int_as_float(p3.y), g3, acc[3]);
    }
    for (; j < e; ++j) {
        int2 p = cpack[j];
        acc[0] = fmaf(__int_as_float(p.y), __bfloat162float(x[p.x * DIM + lane]), acc[0]);
    }
    return ((acc[0] + acc[1]) + (acc[2] + acc[3])) + ((acc[4] + acc[5]) + (acc[6] + acc[7]));
}

// ---- full SpMM: one wave per row ------------------------------------------
__global__ void spmm_k(const bf16* __restrict__ x, const int* __restrict__ rp,
                       const int2* __restrict__ cpack, bf16* __restrict__ y) {
    int row  = (blockIdx.x * blockDim.x + threadIdx.x) >> 6;
    int lane = threadIdx.x & 63;
    if (row >= NTOT) return;
    float a = spmm_row(x, cpack, rp[row], rp[row + 1], lane);
    y[row * DIM + lane] = __float2bfloat16(a);
}

// ---- sliced SpMM for hop 3: only rows the loss reads ----------------------
__global__ void spmm_sliced_k(const bf16* __restrict__ x, const int* __restrict__ rp,
                              const int2* __restrict__ cpack,
                              const int* __restrict__ users, const int* __restrict__ items,
                              const int* __restrict__ negs, bf16* __restrict__ y) {
    int w    = (blockIdx.x * blockDim.x + threadIdx.x) >> 6;
    int lane = threadIdx.x & 63;
    if (w >= NSLICE) return;
    int row = (w < BATCH)     ? users[w]
            : (w < 2 * BATCH) ? NUM_USERS + items[w - BATCH]
                              : NUM_USERS + negs[w - 2 * BATCH];
    float a = spmm_row(x, cpack, rp[row], rp[row + 1], lane);
    y[row * DIM + lane] = __float2bfloat16(a);   // duplicate rows rewrite same value: benign
}

// ---- InfoNCE loss from the four hop buffers (acc/4 on the fly) ------------
__global__ void loss_k(const bf16* __restrict__ x0, const bf16* __restrict__ x1,
                       const bf16* __restrict__ x2, const bf16* __restrict__ x3,
                       const int* __restrict__ users, const int* __restrict__ items,
                       const int* __restrict__ negs, float* __restrict__ loss_accum) {
    int w    = (blockIdx.x * blockDim.x + threadIdx.x) >> 6;
    int lane = threadIdx.x & 63;
    if (w >= BATCH) return;
    auto rowv = [&](int r) -> float {
        int o = r * DIM + lane;
        return (__bfloat162float(x0[o]) + __bfloat162float(x1[o]) +
                __bfloat162float(x2[o]) + __bfloat162float(x3[o])) * 0.25f;
    };
    float ue = rowv(users[w]);
    float ie = rowv(NUM_USERS + items[w]);
    float p = ue * ie;
    for (int o = 32; o > 0; o >>= 1) p += __shfl_xor(p, o, 64);
    float pe = expf(p);
    float ne = 0.0f;
    for (int k = 0; k < NUM_NEG; ++k) {
        float q = ue * rowv(NUM_USERS + negs[k * BATCH + w]);
        for (int o = 32; o > 0; o >>= 1) q += __shfl_xor(q, o, 64);
        ne += expf(q);
    }
    if (lane == 0) atomicAdd(loss_accum, logf((pe + ne) / pe));
}

__global__ void finalize_k(const float* __restrict__ loss_accum, float* __restrict__ out) {
    out[0] = loss_accum[0] * (1.0f / BATCH);
}

__global__ void sentinel_k(float* __restrict__ out) {
    out[0] = -1.0f;
}

extern "C" void kernel_launch(void* const* d_in, const int* in_sizes, int n_in,
                              void* d_out, int out_size, void* d_ws, size_t ws_size,
                              hipStream_t stream) {
    const float* user_emb = (const float*)d_in[0];
    const float* item_emb = (const float*)d_in[1];
    const float* A_vals   = (const float*)d_in[2];
    const int*   A_rows   = (const int*)d_in[3];
    const int*   A_cols   = (const int*)d_in[4];
    const int*   users    = (const int*)d_in[5];
    const int*   items    = (const int*)d_in[6];
    const int*   negs     = (const int*)d_in[7];
    float* out = (float*)d_out;

    char* ws = (char*)d_ws;
    size_t off = 0;
    auto carve = [&](size_t bytes) -> char* {
        char* p = ws + off;
        off = (off + bytes + 255) & ~(size_t)255;
        return p;
    };
    bf16*  x0        = (bf16*)carve((size_t)NTOT * DIM * 2);   // 19.2 MB
    bf16*  x1        = (bf16*)carve((size_t)NTOT * DIM * 2);
    bf16*  x2        = (bf16*)carve((size_t)NTOT * DIM * 2);
    bf16*  x3        = (bf16*)carve((size_t)NTOT * DIM * 2);
    int2*  brec      = (int2*)carve((size_t)NNZ_C * 8);        // 32 MB (binned, then CSR in place)
    int*   rp        = (int*)carve((size_t)(NTOT + 1) * 4);
    int*   bhist     = (int*)carve((size_t)NBUCKET * 4);
    int*   bbase     = (int*)carve((size_t)(NBUCKET + 1) * 4);
    int*   bcur      = (int*)carve((size_t)NBUCKET * 4);
    float* loss_accum= (float*)carve(256);

    if (off > ws_size) {
        sentinel_k<<<1, 1, 0, stream>>>(out);
        return;
    }

    convert_concat<<<(NTOT * DIM / 2 + 255) / 256, 256, 0, stream>>>(user_emb, item_emb, x0, loss_accum);

    // bucketed CSR build
    zero_ints<<<(NBUCKET + 255) / 256, 256, 0, stream>>>(bhist, NBUCKET);
    bucket_hist_k<<<1024, 256, 0, stream>>>(A_rows, bhist);
    bucket_scan_k<<<1, 256, 0, stream>>>(bhist, bbase, bcur);
    bin_k<<<BIN_BLOCKS, 256, 0, stream>>>(A_rows, A_cols, A_vals, bcur, brec);
    csr_fix_k<<<NBUCKET, 256, 0, stream>>>(brec, bbase, rp);

    // hops 1-2 full, hop 3 sliced to loss rows
    const int spmm_blocks = (NTOT * 64 + 255) / 256;
    spmm_k<<<spmm_blocks, 256, 0, stream>>>(x0, rp, brec, x1);
    spmm_k<<<spmm_blocks, 256, 0, stream>>>(x1, rp, brec, x2);
    spmm_sliced_k<<<(NSLICE * 64 + 255) / 256, 256, 0, stream>>>(x2, rp, brec, users, items, negs, x3);

    // loss
    loss_k<<<(BATCH * 64 + 255) / 256, 256, 0, stream>>>(x0, x1, x2, x3, users, items, negs, loss_accum);
    finalize_k<<<1, 1, 0, stream>>>(loss_accum, out);
}